// Round 16
// baseline (205.133 us; speedup 1.0000x reference)
//
#include <hip/hip_runtime.h>
#include <hip/hip_bf16.h>
#include <cstdint>
#include <cstddef>

// GCN 2-layer forward, MI355X (gfx950).
//   CSR build via 2-level BUCKET SORT (no per-edge global atomics)  [R12]
//   W1,W2 -> transposed fp16 planes (one merged kernel)
//   hs = fp16( dinv[m]*(x @ W1h) )   gemm1: fp32 x cast in-kernel, BK=64;
//                                    slice-major [4][N][64] epilogue
//   h1 = fp16( relu(dinv*rowsum(hs)+b1) )   agg: 128B granules, NT gather loads
//   gs = fp16( dinv[m]*(h1 @ W2h) )  gemm2; slice-major [2][N][64]
//   out = relu( dinv*rowsum(gs)+b2 ) fp32
//
// R16: R15's degree-perm was net-negative (divergence is NOT a cost at an
// event-rate-bound kernel; perm scattered rowptr/colv reads) -> reverted to
// R12. Single variable vs R12: gather rows have ZERO L1 reuse (6.4MB slice vs
// 32KB L1), so use __builtin_nontemporal_load (nt flag) to skip L1 allocation.

typedef float f32x4 __attribute__((ext_vector_type(4)));
typedef _Float16 f16x8 __attribute__((ext_vector_type(8)));

#define AS1 __attribute__((address_space(1)))
#define AS3 __attribute__((address_space(3)))
#define BCAP 6144  // bucket capacity (mean 4082, sigma~64)

// ---------------- CSR build: bucket sort ----------------
__global__ __launch_bounds__(256) void k_scatter(const int* __restrict__ src,
                                                 const int* __restrict__ dst,
                                                 int* __restrict__ cursor,
                                                 long long* __restrict__ ebuf, int E) {
    __shared__ int hist[256];
    const int t = threadIdx.x;
    const int chunk = (E + gridDim.x - 1) / gridDim.x;
    const int lo = blockIdx.x * chunk;
    const int hi = (lo + chunk < E) ? lo + chunk : E;
    hist[t] = 0;
    __syncthreads();
    for (int e = lo + t; e < hi; e += 256) atomicAdd(&hist[dst[e] >> 8], 1);
    __syncthreads();
    int h = hist[t];
    __syncthreads();
    if (h > 0) hist[t] = atomicAdd(&cursor[t], h);  // reserve contiguous range
    __syncthreads();
    for (int e = lo + t; e < hi; e += 256) {
        int d = dst[e];
        int r = atomicAdd(&hist[d >> 8], 1);        // LDS rank
        ebuf[(size_t)(d >> 8) * BCAP + r] = ((long long)src[e] << 32) | (unsigned int)d;
    }
}

__global__ __launch_bounds__(256) void k_bktscan(const int* __restrict__ cursor,
                                                 int* __restrict__ bstart) {
    __shared__ int s[256];
    const int t = threadIdx.x;
    int v = cursor[t];
    s[t] = v;
    __syncthreads();
    for (int off = 1; off < 256; off <<= 1) {
        int u = (t >= off) ? s[t - off] : 0;
        __syncthreads();
        s[t] += u;
        __syncthreads();
    }
    bstart[t] = s[t] - v;
}

__global__ __launch_bounds__(256) void k_bktsort(const long long* __restrict__ ebuf,
                                                 const int* __restrict__ cursor,
                                                 const int* __restrict__ bstart,
                                                 int* __restrict__ rowptr,
                                                 int* __restrict__ colv,
                                                 float* __restrict__ dinv,
                                                 int N, int E) {
    __shared__ int hist[256], s[256], cur[256];
    const int b = blockIdx.x, t = threadIdx.x;
    const int cnt = cursor[b], gbase = bstart[b];
    const long long* eb = ebuf + (size_t)b * BCAP;
    hist[t] = 0;
    __syncthreads();
    for (int i = t; i < cnt; i += 256) atomicAdd(&hist[(int)(eb[i] & 255)], 1);
    __syncthreads();
    int h = hist[t];
    s[t] = h;
    __syncthreads();
    for (int off = 1; off < 256; off <<= 1) {
        int u = (t >= off) ? s[t - off] : 0;
        __syncthreads();
        s[t] += u;
        __syncthreads();
    }
    const int base = s[t] - h;       // exclusive within bucket
    cur[t] = gbase + base;
    const int d = b * 256 + t;
    if (d < N) {
        rowptr[d] = gbase + base;
        dinv[d] = rsqrtf((float)(h + 1));
    }
    if (b == 0 && t == 0) rowptr[N] = E;
    __syncthreads();
    for (int i = t; i < cnt; i += 256) {
        long long p = eb[i];
        int r = atomicAdd(&cur[(int)(p & 255)], 1);
        colv[r] = (int)(p >> 32);
    }
}

// ---------------- merged transpose+fp16: W1[R1][C1]->T1[C1][R1], W2 likewise
__global__ __launch_bounds__(256) void k_thalf2(const float* __restrict__ W1,
                                                _Float16* __restrict__ T1,
                                                const float* __restrict__ W2,
                                                _Float16* __restrict__ T2,
                                                int R1, int C1, int R2, int C2) {
    const float* src; _Float16* dh; int R, C;
    if (blockIdx.z == 0) { src = W1; dh = T1; R = R1; C = C1; }
    else                 { src = W2; dh = T2; R = R2; C = C2; }
    if ((int)blockIdx.x * 64 >= C || (int)blockIdx.y * 64 >= R) return;
    __shared__ float tile[64][65];
    int r0 = blockIdx.y * 64, c0 = blockIdx.x * 64;
    for (int i = threadIdx.x; i < 4096; i += 256) {
        int r = i >> 6, c = i & 63;
        tile[r][c] = src[(size_t)(r0 + r) * C + c0 + c];
    }
    __syncthreads();
    for (int i = threadIdx.x; i < 4096; i += 256) {
        int r = i >> 6, c = i & 63;
        dh[(size_t)(c0 + r) * R + r0 + c] = (_Float16)tile[c][r];
    }
}

// ---------------- gemm1: A = fp32 x cast in-kernel, B = fp16 plane -----------
// Epilogue: 64-wide slice-major C[(col>>6)*M + row][col&63].
__global__ __launch_bounds__(256) void k_gemm1(const float* __restrict__ X,
                                               const _Float16* __restrict__ B,
                                               const float* __restrict__ scale,
                                               _Float16* __restrict__ C,
                                               int M, int K, int Nc) {
    __shared__ __align__(16) _Float16 lds[2 * 128 * 64];  // Af | Bf
    _Float16* Afl = lds;
    _Float16* Bfl = lds + 8192;
    const int tid = threadIdx.x;
    const int m0 = blockIdx.x * 128, n0 = blockIdx.y * 128;
    const int w = tid >> 6, lane = tid & 63;
    const int wr = w >> 1, wc = w & 1;
    const int fr = lane & 15, kg = lane >> 4;

    const int arow = tid >> 1;            // staging row 0..127
    const int kf = (tid & 1) * 32;        // float offset within BK
    int rgA = m0 + arow; if (rgA >= M) rgA = M - 1;
    const float* ap0 = X + (size_t)rgA * K + kf;

    f32x4 acc[4][4] = {};

    for (int k0 = 0; k0 < K; k0 += 64) {
#pragma unroll
        for (int c = 0; c < 4; ++c) {
            const int r = c * 4 + w;              // 0..15, wave-uniform
            const int wch = r * 64 + lane;        // 0..1023
            const int row = wch >> 3, slot = wch & 7;
            const _Float16* gp = B + (size_t)(n0 + row) * K + k0 + ((slot ^ (row & 7)) << 3);
            __builtin_amdgcn_global_load_lds((const AS1 void*)gp,
                                             (AS3 void*)(Bfl + (size_t)r * 512), 16, 0, 0);
        }
        {
            const float* ap = ap0 + k0;
#pragma unroll
            for (int c2 = 0; c2 < 4; ++c2) {
                float4 q0 = *(const float4*)(ap + c2 * 8);
                float4 q1 = *(const float4*)(ap + c2 * 8 + 4);
                f16x8 hv;
                hv[0] = (_Float16)q0.x; hv[1] = (_Float16)q0.y;
                hv[2] = (_Float16)q0.z; hv[3] = (_Float16)q0.w;
                hv[4] = (_Float16)q1.x; hv[5] = (_Float16)q1.y;
                hv[6] = (_Float16)q1.z; hv[7] = (_Float16)q1.w;
                const int s = (tid & 1) * 4 + c2;
                *(f16x8*)&Afl[arow * 64 + ((s ^ (arow & 7)) << 3)] = hv;
            }
        }
        __syncthreads();
#pragma unroll
        for (int kc = 0; kc < 2; ++kc) {
            f16x8 a_f[4], b_f[4];
#pragma unroll
            for (int i = 0; i < 4; ++i) {
                const int ar = wr * 64 + i * 16 + fr;
                a_f[i] = *(const f16x8*)&Afl[ar * 64 + (((kc * 4 + kg) ^ (ar & 7)) << 3)];
                const int br = wc * 64 + i * 16 + fr;
                b_f[i] = *(const f16x8*)&Bfl[br * 64 + (((kc * 4 + kg) ^ (br & 7)) << 3)];
            }
#pragma unroll
            for (int i = 0; i < 4; ++i)
#pragma unroll
                for (int j = 0; j < 4; ++j)
                    acc[i][j] = __builtin_amdgcn_mfma_f32_16x16x32_f16(a_f[i], b_f[j], acc[i][j], 0, 0, 0);
        }
        __syncthreads();
    }
    // C/D layout: col=lane&15, row=(lane>>4)*4+reg (m89/m91); 64-slice store.
#pragma unroll
    for (int i = 0; i < 4; ++i) {
        const int rbase = m0 + wr * 64 + i * 16 + (lane >> 4) * 4;
#pragma unroll
        for (int r = 0; r < 4; ++r) {
            const int row = rbase + r;
            if (row < M) {
                const float s = scale[row];
#pragma unroll
                for (int j = 0; j < 4; ++j) {
                    const int col = n0 + wc * 64 + j * 16 + fr;
                    const size_t o = ((size_t)(col >> 6) * M + row) * 64 + (col & 63);
                    C[o] = (_Float16)(acc[i][j][r] * s);
                }
            }
        }
    }
}

// ---------------- gemm2: A,B fp16 planes via global_load_lds ----------------
__global__ __launch_bounds__(256) void k_gemm2(const _Float16* __restrict__ Ap,
                                               const _Float16* __restrict__ Bp,
                                               const float* __restrict__ scale,
                                               _Float16* __restrict__ C,
                                               int M, int K, int Nc) {
    __shared__ __align__(16) _Float16 lds[2 * 128 * 64];  // Af | Bf
    const int tid = threadIdx.x;
    const int m0 = blockIdx.x * 128, n0 = blockIdx.y * 128;
    const int w = tid >> 6, lane = tid & 63;
    const int wr = w >> 1, wc = w & 1;
    const int fr = lane & 15, kg = lane >> 4;

    f32x4 acc[4][4] = {};

    for (int k0 = 0; k0 < K; k0 += 64) {
#pragma unroll
        for (int c = 0; c < 8; ++c) {
            const int r = c * 4 + w;              // 0..31, wave-uniform
            const int p = r >> 4;                 // plane, wave-uniform
            const int wch = (r & 15) * 64 + lane; // 0..1023
            const int row = wch >> 3, slot = wch & 7;
            const int swz = (slot ^ (row & 7)) << 3;
            const _Float16* gp;
            if (p == 0) {
                int rg = m0 + row; if (rg >= M) rg = M - 1;
                gp = Ap + (size_t)rg * K + k0 + swz;
            } else {
                gp = Bp + (size_t)(n0 + row) * K + k0 + swz;
            }
            __builtin_amdgcn_global_load_lds((const AS1 void*)gp,
                                             (AS3 void*)(lds + (size_t)r * 512), 16, 0, 0);
        }
        __syncthreads();
#pragma unroll
        for (int kc = 0; kc < 2; ++kc) {
            f16x8 a_f[4], b_f[4];
#pragma unroll
            for (int i = 0; i < 4; ++i) {
                const int ar = wr * 64 + i * 16 + fr;
                a_f[i] = *(const f16x8*)&lds[ar * 64 + (((kc * 4 + kg) ^ (ar & 7)) << 3)];
                const int br = wc * 64 + i * 16 + fr;
                b_f[i] = *(const f16x8*)&lds[8192 + br * 64 + (((kc * 4 + kg) ^ (br & 7)) << 3)];
            }
#pragma unroll
            for (int i = 0; i < 4; ++i)
#pragma unroll
                for (int j = 0; j < 4; ++j)
                    acc[i][j] = __builtin_amdgcn_mfma_f32_16x16x32_f16(a_f[i], b_f[j], acc[i][j], 0, 0, 0);
        }
        __syncthreads();
    }
#pragma unroll
    for (int i = 0; i < 4; ++i) {
        const int rbase = m0 + wr * 64 + i * 16 + (lane >> 4) * 4;
#pragma unroll
        for (int r = 0; r < 4; ++r) {
            const int row = rbase + r;
            if (row < M) {
                const float s = scale[row];
#pragma unroll
                for (int j = 0; j < 4; ++j) {
                    const int col = n0 + wc * 64 + j * 16 + fr;
                    const size_t o = ((size_t)(col >> 6) * M + row) * 64 + (col & 63);
                    C[o] = (_Float16)(acc[i][j][r] * s);
                }
            }
        }
    }
}

// ---------------- aggregation: 128B granules, NT gather loads ----------------
// Table slice-major [NSLICE][n][64] fp16 (pre-scaled by dinv[src]).
// One 8-LANE subgroup per (node,slice); gather rows loaded with
// __builtin_nontemporal_load (zero L1 reuse -> skip L1 allocation).
template <int NSLICE, bool OUTF16>
__global__ __launch_bounds__(256) void k_agg_gr(const _Float16* __restrict__ tbl0,
                                                const int* __restrict__ rowptr,
                                                const int* __restrict__ colv,
                                                const float* __restrict__ dinv,
                                                const float* __restrict__ bias,
                                                float* __restrict__ outf,
                                                _Float16* __restrict__ outh, int n) {
    constexpr int F = NSLICE * 64;
    const int slice = blockIdx.x;
    const int g = threadIdx.x >> 3;      // subgroup 0..31 = node within block
    const int li = threadIdx.x & 7;
    const int fb = li * 8;               // feature offset within slice
    const int wid = blockIdx.y * 32 + g;
    if (wid >= n) return;
    const _Float16* tbl = tbl0 + (size_t)slice * n * 64 + fb;

    float acc[8];
    {   // self row (pre-scaled by dinv[wid] in GEMM epilogue)
        f16x8 v = *(const f16x8*)(tbl + (size_t)wid * 64);
#pragma unroll
        for (int j = 0; j < 8; ++j) acc[j] = (float)v[j];
    }
    const int p0 = rowptr[wid], p1 = rowptr[wid + 1];
    int p = p0;
    for (; p + 4 <= p1; p += 4) {
        int s0 = colv[p], s1 = colv[p + 1], s2 = colv[p + 2], s3 = colv[p + 3];
        f16x8 v0 = __builtin_nontemporal_load((const f16x8*)(tbl + (size_t)s0 * 64));
        f16x8 v1 = __builtin_nontemporal_load((const f16x8*)(tbl + (size_t)s1 * 64));
        f16x8 v2 = __builtin_nontemporal_load((const f16x8*)(tbl + (size_t)s2 * 64));
        f16x8 v3 = __builtin_nontemporal_load((const f16x8*)(tbl + (size_t)s3 * 64));
#pragma unroll
        for (int j = 0; j < 8; ++j)
            acc[j] += ((float)v0[j] + (float)v1[j]) + ((float)v2[j] + (float)v3[j]);
    }
    for (; p < p1; ++p) {
        f16x8 v = __builtin_nontemporal_load((const f16x8*)(tbl + (size_t)colv[p] * 64));
#pragma unroll
        for (int j = 0; j < 8; ++j) acc[j] += (float)v[j];
    }
    const float di = dinv[wid];
    float r[8];
#pragma unroll
    for (int j = 0; j < 8; ++j) {
        float t = di * acc[j] + bias[slice * 64 + fb + j];
        r[j] = t > 0.f ? t : 0.f;
    }
    const size_t o = (size_t)wid * F + slice * 64 + fb;
    if constexpr (OUTF16) {
        f16x8 hv;
#pragma unroll
        for (int j = 0; j < 8; ++j) hv[j] = (_Float16)r[j];
        *(f16x8*)(outh + o) = hv;
    } else {
        float* op = outf + o;
        *(float4*)(op)     = make_float4(r[0], r[1], r[2], r[3]);
        *(float4*)(op + 4) = make_float4(r[4], r[5], r[6], r[7]);
    }
}

extern "C" void kernel_launch(void* const* d_in, const int* in_sizes, int n_in,
                              void* d_out, int out_size, void* d_ws, size_t ws_size,
                              hipStream_t stream) {
    const float* x  = (const float*)d_in[0];
    const int*   ei = (const int*)d_in[1];
    const float* W1 = (const float*)d_in[2];
    const float* b1 = (const float*)d_in[3];
    const float* W2 = (const float*)d_in[4];
    const float* b2 = (const float*)d_in[5];

    const int HID = in_sizes[3];            // 256
    const int IN  = in_sizes[2] / HID;      // 256
    const int OUT = in_sizes[5];            // 128
    const int N   = in_sizes[0] / IN;       // 50000
    const int E   = in_sizes[1] / 2;        // 800000

    const int* src = ei;
    const int* dst = ei + E;

    char* wsb = (char*)d_ws;
    size_t off = 0;
    auto carve = [&](size_t bytes) -> char* {
        char* p = wsb + off;
        off += (bytes + 255) & ~(size_t)255;
        return p;
    };
    _Float16* h1  = (_Float16*)carve((size_t)N * HID * 2);  // row-major fp16
    _Float16* hsb = (_Float16*)carve((size_t)N * HID * 2);  // slice-major [4][N][64]
    _Float16* gsb = (_Float16*)carve((size_t)N * OUT * 2);  // slice-major [2][N][64]
    float* dinv   = (float*)carve((size_t)N * 4);
    int*   rowptr = (int*)carve((size_t)(N + 1) * 4);
    int*   colv   = (int*)carve((size_t)E * 4);
    long long* ebuf = (long long*)carve((size_t)256 * BCAP * 8);
    int*   cursor = (int*)carve(1024);
    int*   bstart = (int*)carve(1024);
    _Float16* W1Th = (_Float16*)carve((size_t)IN * HID * 2);
    _Float16* W2Th = (_Float16*)carve((size_t)HID * OUT * 2);
    (void)ws_size; (void)n_in; (void)out_size;

    const int nbkt = (N + 255) >> 8;   // 196 buckets
    const int ybN = (N + 31) / 32;     // one 8-lane subgroup per node

    // CSR via bucket sort (no per-edge global atomics)
    hipMemsetAsync(cursor, 0, 1024, stream);
    k_scatter<<<256, 256, 0, stream>>>(src, dst, cursor, ebuf, E);
    k_bktscan<<<1, 256, 0, stream>>>(cursor, bstart);
    k_bktsort<<<nbkt, 256, 0, stream>>>(ebuf, cursor, bstart, rowptr, colv, dinv, N, E);

    // merged weight transposes (fp16 planes)
    k_thalf2<<<dim3(4, 4, 2), 256, 0, stream>>>(W1, W1Th, W2, W2Th, IN, HID, HID, OUT);

    // layer 1 (x fp16-cast fused into gemm1)
    k_gemm1<<<dim3((N + 127) / 128, HID / 128), 256, 0, stream>>>(
        x, W1Th, dinv, hsb, N, IN, HID);
    k_agg_gr<4, true><<<dim3(4, ybN), 256, 0, stream>>>(
        hsb, rowptr, colv, dinv, b1, nullptr, h1, N);
    // layer 2
    k_gemm2<<<dim3((N + 127) / 128, OUT / 128), 256, 0, stream>>>(
        h1, W2Th, dinv, gsb, N, HID, OUT);
    k_agg_gr<2, false><<<dim3(2, ybN), 256, 0, stream>>>(
        gsb, rowptr, colv, dinv, b2, (float*)d_out, nullptr, N);
}

// Round 17
// 165.552 us; speedup vs baseline: 1.2391x; 1.2391x over previous
//
#include <hip/hip_runtime.h>
#include <hip/hip_bf16.h>
#include <cstdint>
#include <cstddef>

// GCN 2-layer forward, MI355X (gfx950).
//   CSR build via 2-level BUCKET SORT (no per-edge global atomics)  [R12]
//     (bucket-total scan folded into k_bktsort [R17])
//   W1,W2 -> transposed fp16 planes (one merged kernel)
//   hs = fp16( dinv[m]*(x @ W1h) )   gemm1: fp32 x cast in-kernel, BK=64;
//                                    slice-major [4][N][64] epilogue
//   h1 = fp16( relu(dinv*rowsum(hs)+b1) )   agg: 128B granules, 8-deep unroll
//   gs = fp16( dinv[m]*(h1 @ W2h) )  gemm2; slice-major [2][N][64]
//   out = relu( dinv*rowsum(gs)+b2 ) fp32
//
// R17: R16's nt-loads regressed (nt demotes L2 retention too -> table fell
// out of cache; 45->72us). Reverted. Agg is latency x concurrency bound
// (20 waves/CU x 4 inflight x ~300cyc = measured 45us), so deepen the
// gather unroll 4->8. Also: bktscan folded into bktsort (one less dispatch).

typedef float f32x4 __attribute__((ext_vector_type(4)));
typedef _Float16 f16x8 __attribute__((ext_vector_type(8)));

#define AS1 __attribute__((address_space(1)))
#define AS3 __attribute__((address_space(3)))
#define BCAP 6144  // bucket capacity (mean 4082, sigma~64)

// ---------------- CSR build: bucket sort ----------------
__global__ __launch_bounds__(256) void k_scatter(const int* __restrict__ src,
                                                 const int* __restrict__ dst,
                                                 int* __restrict__ cursor,
                                                 long long* __restrict__ ebuf, int E) {
    __shared__ int hist[256];
    const int t = threadIdx.x;
    const int chunk = (E + gridDim.x - 1) / gridDim.x;
    const int lo = blockIdx.x * chunk;
    const int hi = (lo + chunk < E) ? lo + chunk : E;
    hist[t] = 0;
    __syncthreads();
    for (int e = lo + t; e < hi; e += 256) atomicAdd(&hist[dst[e] >> 8], 1);
    __syncthreads();
    int h = hist[t];
    __syncthreads();
    if (h > 0) hist[t] = atomicAdd(&cursor[t], h);  // reserve contiguous range
    __syncthreads();
    for (int e = lo + t; e < hi; e += 256) {
        int d = dst[e];
        int r = atomicAdd(&hist[d >> 8], 1);        // LDS rank
        ebuf[(size_t)(d >> 8) * BCAP + r] = ((long long)src[e] << 32) | (unsigned int)d;
    }
}

// counting sort per bucket; bucket-total scan done in-block (no k_bktscan)
__global__ __launch_bounds__(256) void k_bktsort(const long long* __restrict__ ebuf,
                                                 const int* __restrict__ cursor,
                                                 int* __restrict__ rowptr,
                                                 int* __restrict__ colv,
                                                 float* __restrict__ dinv,
                                                 int N, int E) {
    __shared__ int hist[256], s[256], cur[256];
    __shared__ int gbase_sh;
    const int b = blockIdx.x, t = threadIdx.x;
    // block-local exclusive scan of all bucket totals -> gbase for bucket b
    int cv = cursor[t];
    s[t] = cv;
    __syncthreads();
    for (int off = 1; off < 256; off <<= 1) {
        int u = (t >= off) ? s[t - off] : 0;
        __syncthreads();
        s[t] += u;
        __syncthreads();
    }
    if (t == b) gbase_sh = s[t] - cv;
    __syncthreads();
    const int gbase = gbase_sh;
    const int cnt = cursor[b];
    const long long* eb = ebuf + (size_t)b * BCAP;

    hist[t] = 0;
    __syncthreads();
    for (int i = t; i < cnt; i += 256) atomicAdd(&hist[(int)(eb[i] & 255)], 1);
    __syncthreads();
    int h = hist[t];
    s[t] = h;
    __syncthreads();
    for (int off = 1; off < 256; off <<= 1) {
        int u = (t >= off) ? s[t - off] : 0;
        __syncthreads();
        s[t] += u;
        __syncthreads();
    }
    const int base = s[t] - h;       // exclusive within bucket
    cur[t] = gbase + base;
    const int d = b * 256 + t;
    if (d < N) {
        rowptr[d] = gbase + base;
        dinv[d] = rsqrtf((float)(h + 1));
    }
    if (b == 0 && t == 0) rowptr[N] = E;
    __syncthreads();
    for (int i = t; i < cnt; i += 256) {
        long long p = eb[i];
        int r = atomicAdd(&cur[(int)(p & 255)], 1);
        colv[r] = (int)(p >> 32);
    }
}

// ---------------- merged transpose+fp16: W1[R1][C1]->T1[C1][R1], W2 likewise
__global__ __launch_bounds__(256) void k_thalf2(const float* __restrict__ W1,
                                                _Float16* __restrict__ T1,
                                                const float* __restrict__ W2,
                                                _Float16* __restrict__ T2,
                                                int R1, int C1, int R2, int C2) {
    const float* src; _Float16* dh; int R, C;
    if (blockIdx.z == 0) { src = W1; dh = T1; R = R1; C = C1; }
    else                 { src = W2; dh = T2; R = R2; C = C2; }
    if ((int)blockIdx.x * 64 >= C || (int)blockIdx.y * 64 >= R) return;
    __shared__ float tile[64][65];
    int r0 = blockIdx.y * 64, c0 = blockIdx.x * 64;
    for (int i = threadIdx.x; i < 4096; i += 256) {
        int r = i >> 6, c = i & 63;
        tile[r][c] = src[(size_t)(r0 + r) * C + c0 + c];
    }
    __syncthreads();
    for (int i = threadIdx.x; i < 4096; i += 256) {
        int r = i >> 6, c = i & 63;
        dh[(size_t)(c0 + r) * R + r0 + c] = (_Float16)tile[c][r];
    }
}

// ---------------- gemm1: A = fp32 x cast in-kernel, B = fp16 plane -----------
// Epilogue: 64-wide slice-major C[(col>>6)*M + row][col&63].
__global__ __launch_bounds__(256) void k_gemm1(const float* __restrict__ X,
                                               const _Float16* __restrict__ B,
                                               const float* __restrict__ scale,
                                               _Float16* __restrict__ C,
                                               int M, int K, int Nc) {
    __shared__ __align__(16) _Float16 lds[2 * 128 * 64];  // Af | Bf
    _Float16* Afl = lds;
    _Float16* Bfl = lds + 8192;
    const int tid = threadIdx.x;
    const int m0 = blockIdx.x * 128, n0 = blockIdx.y * 128;
    const int w = tid >> 6, lane = tid & 63;
    const int wr = w >> 1, wc = w & 1;
    const int fr = lane & 15, kg = lane >> 4;

    const int arow = tid >> 1;            // staging row 0..127
    const int kf = (tid & 1) * 32;        // float offset within BK
    int rgA = m0 + arow; if (rgA >= M) rgA = M - 1;
    const float* ap0 = X + (size_t)rgA * K + kf;

    f32x4 acc[4][4] = {};

    for (int k0 = 0; k0 < K; k0 += 64) {
#pragma unroll
        for (int c = 0; c < 4; ++c) {
            const int r = c * 4 + w;              // 0..15, wave-uniform
            const int wch = r * 64 + lane;        // 0..1023
            const int row = wch >> 3, slot = wch & 7;
            const _Float16* gp = B + (size_t)(n0 + row) * K + k0 + ((slot ^ (row & 7)) << 3);
            __builtin_amdgcn_global_load_lds((const AS1 void*)gp,
                                             (AS3 void*)(Bfl + (size_t)r * 512), 16, 0, 0);
        }
        {
            const float* ap = ap0 + k0;
#pragma unroll
            for (int c2 = 0; c2 < 4; ++c2) {
                float4 q0 = *(const float4*)(ap + c2 * 8);
                float4 q1 = *(const float4*)(ap + c2 * 8 + 4);
                f16x8 hv;
                hv[0] = (_Float16)q0.x; hv[1] = (_Float16)q0.y;
                hv[2] = (_Float16)q0.z; hv[3] = (_Float16)q0.w;
                hv[4] = (_Float16)q1.x; hv[5] = (_Float16)q1.y;
                hv[6] = (_Float16)q1.z; hv[7] = (_Float16)q1.w;
                const int s = (tid & 1) * 4 + c2;
                *(f16x8*)&Afl[arow * 64 + ((s ^ (arow & 7)) << 3)] = hv;
            }
        }
        __syncthreads();
#pragma unroll
        for (int kc = 0; kc < 2; ++kc) {
            f16x8 a_f[4], b_f[4];
#pragma unroll
            for (int i = 0; i < 4; ++i) {
                const int ar = wr * 64 + i * 16 + fr;
                a_f[i] = *(const f16x8*)&Afl[ar * 64 + (((kc * 4 + kg) ^ (ar & 7)) << 3)];
                const int br = wc * 64 + i * 16 + fr;
                b_f[i] = *(const f16x8*)&Bfl[br * 64 + (((kc * 4 + kg) ^ (br & 7)) << 3)];
            }
#pragma unroll
            for (int i = 0; i < 4; ++i)
#pragma unroll
                for (int j = 0; j < 4; ++j)
                    acc[i][j] = __builtin_amdgcn_mfma_f32_16x16x32_f16(a_f[i], b_f[j], acc[i][j], 0, 0, 0);
        }
        __syncthreads();
    }
    // C/D layout: col=lane&15, row=(lane>>4)*4+reg (m89/m91); 64-slice store.
#pragma unroll
    for (int i = 0; i < 4; ++i) {
        const int rbase = m0 + wr * 64 + i * 16 + (lane >> 4) * 4;
#pragma unroll
        for (int r = 0; r < 4; ++r) {
            const int row = rbase + r;
            if (row < M) {
                const float s = scale[row];
#pragma unroll
                for (int j = 0; j < 4; ++j) {
                    const int col = n0 + wc * 64 + j * 16 + fr;
                    const size_t o = ((size_t)(col >> 6) * M + row) * 64 + (col & 63);
                    C[o] = (_Float16)(acc[i][j][r] * s);
                }
            }
        }
    }
}

// ---------------- gemm2: A,B fp16 planes via global_load_lds ----------------
__global__ __launch_bounds__(256) void k_gemm2(const _Float16* __restrict__ Ap,
                                               const _Float16* __restrict__ Bp,
                                               const float* __restrict__ scale,
                                               _Float16* __restrict__ C,
                                               int M, int K, int Nc) {
    __shared__ __align__(16) _Float16 lds[2 * 128 * 64];  // Af | Bf
    const int tid = threadIdx.x;
    const int m0 = blockIdx.x * 128, n0 = blockIdx.y * 128;
    const int w = tid >> 6, lane = tid & 63;
    const int wr = w >> 1, wc = w & 1;
    const int fr = lane & 15, kg = lane >> 4;

    f32x4 acc[4][4] = {};

    for (int k0 = 0; k0 < K; k0 += 64) {
#pragma unroll
        for (int c = 0; c < 8; ++c) {
            const int r = c * 4 + w;              // 0..31, wave-uniform
            const int p = r >> 4;                 // plane, wave-uniform
            const int wch = (r & 15) * 64 + lane; // 0..1023
            const int row = wch >> 3, slot = wch & 7;
            const int swz = (slot ^ (row & 7)) << 3;
            const _Float16* gp;
            if (p == 0) {
                int rg = m0 + row; if (rg >= M) rg = M - 1;
                gp = Ap + (size_t)rg * K + k0 + swz;
            } else {
                gp = Bp + (size_t)(n0 + row) * K + k0 + swz;
            }
            __builtin_amdgcn_global_load_lds((const AS1 void*)gp,
                                             (AS3 void*)(lds + (size_t)r * 512), 16, 0, 0);
        }
        __syncthreads();
#pragma unroll
        for (int kc = 0; kc < 2; ++kc) {
            f16x8 a_f[4], b_f[4];
#pragma unroll
            for (int i = 0; i < 4; ++i) {
                const int ar = wr * 64 + i * 16 + fr;
                a_f[i] = *(const f16x8*)&lds[ar * 64 + (((kc * 4 + kg) ^ (ar & 7)) << 3)];
                const int br = wc * 64 + i * 16 + fr;
                b_f[i] = *(const f16x8*)&lds[8192 + br * 64 + (((kc * 4 + kg) ^ (br & 7)) << 3)];
            }
#pragma unroll
            for (int i = 0; i < 4; ++i)
#pragma unroll
                for (int j = 0; j < 4; ++j)
                    acc[i][j] = __builtin_amdgcn_mfma_f32_16x16x32_f16(a_f[i], b_f[j], acc[i][j], 0, 0, 0);
        }
        __syncthreads();
    }
#pragma unroll
    for (int i = 0; i < 4; ++i) {
        const int rbase = m0 + wr * 64 + i * 16 + (lane >> 4) * 4;
#pragma unroll
        for (int r = 0; r < 4; ++r) {
            const int row = rbase + r;
            if (row < M) {
                const float s = scale[row];
#pragma unroll
                for (int j = 0; j < 4; ++j) {
                    const int col = n0 + wc * 64 + j * 16 + fr;
                    const size_t o = ((size_t)(col >> 6) * M + row) * 64 + (col & 63);
                    C[o] = (_Float16)(acc[i][j][r] * s);
                }
            }
        }
    }
}

// ---------------- aggregation: 128B granules, 8-deep gather unroll ----------
// Table slice-major [NSLICE][n][64] fp16 (pre-scaled by dinv[src]).
// One 8-LANE subgroup per (node,slice); 8 independent 128B gathers in flight.
template <int NSLICE, bool OUTF16>
__global__ __launch_bounds__(256) void k_agg_gr(const _Float16* __restrict__ tbl0,
                                                const int* __restrict__ rowptr,
                                                const int* __restrict__ colv,
                                                const float* __restrict__ dinv,
                                                const float* __restrict__ bias,
                                                float* __restrict__ outf,
                                                _Float16* __restrict__ outh, int n) {
    constexpr int F = NSLICE * 64;
    const int slice = blockIdx.x;
    const int g = threadIdx.x >> 3;      // subgroup 0..31 = node within block
    const int li = threadIdx.x & 7;
    const int fb = li * 8;               // feature offset within slice
    const int wid = blockIdx.y * 32 + g;
    if (wid >= n) return;
    const _Float16* tbl = tbl0 + (size_t)slice * n * 64 + fb;

    float acc[8];
    {   // self row (pre-scaled by dinv[wid] in GEMM epilogue)
        f16x8 v = *(const f16x8*)(tbl + (size_t)wid * 64);
#pragma unroll
        for (int j = 0; j < 8; ++j) acc[j] = (float)v[j];
    }
    const int p0 = rowptr[wid], p1 = rowptr[wid + 1];
    int p = p0;
    for (; p + 8 <= p1; p += 8) {        // 8 gathers in flight
        int sx[8];
#pragma unroll
        for (int u = 0; u < 8; ++u) sx[u] = colv[p + u];
        f16x8 v[8];
#pragma unroll
        for (int u = 0; u < 8; ++u) v[u] = *(const f16x8*)(tbl + (size_t)sx[u] * 64);
#pragma unroll
        for (int j = 0; j < 8; ++j)
            acc[j] += (((float)v[0][j] + (float)v[1][j]) + ((float)v[2][j] + (float)v[3][j]))
                    + (((float)v[4][j] + (float)v[5][j]) + ((float)v[6][j] + (float)v[7][j]));
    }
    if (p + 4 <= p1) {
        int s0 = colv[p], s1 = colv[p + 1], s2 = colv[p + 2], s3 = colv[p + 3];
        f16x8 v0 = *(const f16x8*)(tbl + (size_t)s0 * 64);
        f16x8 v1 = *(const f16x8*)(tbl + (size_t)s1 * 64);
        f16x8 v2 = *(const f16x8*)(tbl + (size_t)s2 * 64);
        f16x8 v3 = *(const f16x8*)(tbl + (size_t)s3 * 64);
#pragma unroll
        for (int j = 0; j < 8; ++j)
            acc[j] += ((float)v0[j] + (float)v1[j]) + ((float)v2[j] + (float)v3[j]);
        p += 4;
    }
    for (; p < p1; ++p) {
        f16x8 v = *(const f16x8*)(tbl + (size_t)colv[p] * 64);
#pragma unroll
        for (int j = 0; j < 8; ++j) acc[j] += (float)v[j];
    }
    const float di = dinv[wid];
    float r[8];
#pragma unroll
    for (int j = 0; j < 8; ++j) {
        float t = di * acc[j] + bias[slice * 64 + fb + j];
        r[j] = t > 0.f ? t : 0.f;
    }
    const size_t o = (size_t)wid * F + slice * 64 + fb;
    if constexpr (OUTF16) {
        f16x8 hv;
#pragma unroll
        for (int j = 0; j < 8; ++j) hv[j] = (_Float16)r[j];
        *(f16x8*)(outh + o) = hv;
    } else {
        float* op = outf + o;
        *(float4*)(op)     = make_float4(r[0], r[1], r[2], r[3]);
        *(float4*)(op + 4) = make_float4(r[4], r[5], r[6], r[7]);
    }
}

extern "C" void kernel_launch(void* const* d_in, const int* in_sizes, int n_in,
                              void* d_out, int out_size, void* d_ws, size_t ws_size,
                              hipStream_t stream) {
    const float* x  = (const float*)d_in[0];
    const int*   ei = (const int*)d_in[1];
    const float* W1 = (const float*)d_in[2];
    const float* b1 = (const float*)d_in[3];
    const float* W2 = (const float*)d_in[4];
    const float* b2 = (const float*)d_in[5];

    const int HID = in_sizes[3];            // 256
    const int IN  = in_sizes[2] / HID;      // 256
    const int OUT = in_sizes[5];            // 128
    const int N   = in_sizes[0] / IN;       // 50000
    const int E   = in_sizes[1] / 2;        // 800000

    const int* src = ei;
    const int* dst = ei + E;

    char* wsb = (char*)d_ws;
    size_t off = 0;
    auto carve = [&](size_t bytes) -> char* {
        char* p = wsb + off;
        off += (bytes + 255) & ~(size_t)255;
        return p;
    };
    _Float16* h1  = (_Float16*)carve((size_t)N * HID * 2);  // row-major fp16
    _Float16* hsb = (_Float16*)carve((size_t)N * HID * 2);  // slice-major [4][N][64]
    _Float16* gsb = (_Float16*)carve((size_t)N * OUT * 2);  // slice-major [2][N][64]
    float* dinv   = (float*)carve((size_t)N * 4);
    int*   rowptr = (int*)carve((size_t)(N + 1) * 4);
    int*   colv   = (int*)carve((size_t)E * 4);
    long long* ebuf = (long long*)carve((size_t)256 * BCAP * 8);
    int*   cursor = (int*)carve(1024);
    _Float16* W1Th = (_Float16*)carve((size_t)IN * HID * 2);
    _Float16* W2Th = (_Float16*)carve((size_t)HID * OUT * 2);
    (void)ws_size; (void)n_in; (void)out_size;

    const int nbkt = (N + 255) >> 8;   // 196 buckets
    const int ybN = (N + 31) / 32;     // one 8-lane subgroup per node

    // CSR via bucket sort (no per-edge global atomics)
    hipMemsetAsync(cursor, 0, 1024, stream);
    k_scatter<<<256, 256, 0, stream>>>(src, dst, cursor, ebuf, E);
    k_bktsort<<<nbkt, 256, 0, stream>>>(ebuf, cursor, rowptr, colv, dinv, N, E);

    // merged weight transposes (fp16 planes)
    k_thalf2<<<dim3(4, 4, 2), 256, 0, stream>>>(W1, W1Th, W2, W2Th, IN, HID, HID, OUT);

    // layer 1 (x fp16-cast fused into gemm1)
    k_gemm1<<<dim3((N + 127) / 128, HID / 128), 256, 0, stream>>>(
        x, W1Th, dinv, hsb, N, IN, HID);
    k_agg_gr<4, true><<<dim3(4, ybN), 256, 0, stream>>>(
        hsb, rowptr, colv, dinv, b1, nullptr, h1, N);
    // layer 2
    k_gemm2<<<dim3((N + 127) / 128, OUT / 128), 256, 0, stream>>>(
        h1, W2Th, dinv, gsb, N, HID, OUT);
    k_agg_gr<2, false><<<dim3(2, ybN), 256, 0, stream>>>(
        gsb, rowptr, colv, dinv, b2, (float*)d_out, nullptr, N);
}

// Round 18
// 157.718 us; speedup vs baseline: 1.3006x; 1.0497x over previous
//
#include <hip/hip_runtime.h>
#include <hip/hip_bf16.h>
#include <cstdint>
#include <cstddef>

// GCN 2-layer forward, MI355X (gfx950).  R18 = consolidation:
//   CSR via 2-level bucket sort [R12], bktscan folded into bktsort [R17]
//   W1,W2 -> transposed fp16 planes (one merged kernel)
//   hs = fp16( dinv[m]*(x @ W1h) )  gemm1: fp32 x cast in-kernel, BK=64,
//                                   slice-major [4][N][64] epilogue
//   h1 = fp16( relu(dinv*rowsum(hs)+b1) )  agg: 128B granules, 4-deep (R12)
//   gs = fp16( dinv[m]*(h1 @ W2h) ) gemm2; slice-major [2][N][64]
//   out = relu( dinv*rowsum(gs)+b2 ) fp32
//
// Agg floor (5-way probed R13/R15/R16/R17): ~4cyc per 64B L1-line miss per CU
// -> agg1 ~45us, agg2 ~23us. 128B granule / 4-deep / plain loads is optimal.

typedef float f32x4 __attribute__((ext_vector_type(4)));
typedef _Float16 f16x8 __attribute__((ext_vector_type(8)));

#define AS1 __attribute__((address_space(1)))
#define AS3 __attribute__((address_space(3)))
#define BCAP 6144  // bucket capacity (mean 4082, sigma~64)

// ---------------- CSR build: bucket sort ----------------
__global__ __launch_bounds__(256) void k_scatter(const int* __restrict__ src,
                                                 const int* __restrict__ dst,
                                                 int* __restrict__ cursor,
                                                 long long* __restrict__ ebuf, int E) {
    __shared__ int hist[256];
    const int t = threadIdx.x;
    const int chunk = (E + gridDim.x - 1) / gridDim.x;
    const int lo = blockIdx.x * chunk;
    const int hi = (lo + chunk < E) ? lo + chunk : E;
    hist[t] = 0;
    __syncthreads();
    for (int e = lo + t; e < hi; e += 256) atomicAdd(&hist[dst[e] >> 8], 1);
    __syncthreads();
    int h = hist[t];
    __syncthreads();
    if (h > 0) hist[t] = atomicAdd(&cursor[t], h);  // reserve contiguous range
    __syncthreads();
    int e = lo + t * 4;
    const int step = 256 * 4;
    for (; e + 4 <= hi; e += step) {
        int d0 = dst[e], d1 = dst[e + 1], d2 = dst[e + 2], d3 = dst[e + 3];
        int s0 = src[e], s1 = src[e + 1], s2 = src[e + 2], s3 = src[e + 3];
        int r0 = atomicAdd(&hist[d0 >> 8], 1);
        int r1 = atomicAdd(&hist[d1 >> 8], 1);
        int r2 = atomicAdd(&hist[d2 >> 8], 1);
        int r3 = atomicAdd(&hist[d3 >> 8], 1);
        ebuf[(size_t)(d0 >> 8) * BCAP + r0] = ((long long)s0 << 32) | (unsigned int)d0;
        ebuf[(size_t)(d1 >> 8) * BCAP + r1] = ((long long)s1 << 32) | (unsigned int)d1;
        ebuf[(size_t)(d2 >> 8) * BCAP + r2] = ((long long)s2 << 32) | (unsigned int)d2;
        ebuf[(size_t)(d3 >> 8) * BCAP + r3] = ((long long)s3 << 32) | (unsigned int)d3;
    }
    for (; e < hi; ++e) {
        int d = dst[e];
        int r = atomicAdd(&hist[d >> 8], 1);
        ebuf[(size_t)(d >> 8) * BCAP + r] = ((long long)src[e] << 32) | (unsigned int)d;
    }
}

// counting sort per bucket; bucket-total scan done in-block (no k_bktscan)
__global__ __launch_bounds__(256) void k_bktsort(const long long* __restrict__ ebuf,
                                                 const int* __restrict__ cursor,
                                                 int* __restrict__ rowptr,
                                                 int* __restrict__ colv,
                                                 float* __restrict__ dinv,
                                                 int N, int E) {
    __shared__ int hist[256], s[256], cur[256];
    __shared__ int gbase_sh;
    const int b = blockIdx.x, t = threadIdx.x;
    // block-local exclusive scan of all bucket totals -> gbase for bucket b
    int cv = cursor[t];
    s[t] = cv;
    __syncthreads();
    for (int off = 1; off < 256; off <<= 1) {
        int u = (t >= off) ? s[t - off] : 0;
        __syncthreads();
        s[t] += u;
        __syncthreads();
    }
    if (t == b) gbase_sh = s[t] - cv;
    __syncthreads();
    const int gbase = gbase_sh;
    const int cnt = cursor[b];
    const long long* eb = ebuf + (size_t)b * BCAP;

    hist[t] = 0;
    __syncthreads();
    for (int i = t; i < cnt; i += 256) atomicAdd(&hist[(int)(eb[i] & 255)], 1);
    __syncthreads();
    int h = hist[t];
    s[t] = h;
    __syncthreads();
    for (int off = 1; off < 256; off <<= 1) {
        int u = (t >= off) ? s[t - off] : 0;
        __syncthreads();
        s[t] += u;
        __syncthreads();
    }
    const int base = s[t] - h;       // exclusive within bucket
    cur[t] = gbase + base;
    const int d = b * 256 + t;
    if (d < N) {
        rowptr[d] = gbase + base;
        dinv[d] = rsqrtf((float)(h + 1));
    }
    if (b == 0 && t == 0) rowptr[N] = E;
    __syncthreads();
    for (int i = t; i < cnt; i += 256) {
        long long p = eb[i];
        int r = atomicAdd(&cur[(int)(p & 255)], 1);
        colv[r] = (int)(p >> 32);
    }
}

// ---------------- merged transpose+fp16: W1[R1][C1]->T1[C1][R1], W2 likewise
__global__ __launch_bounds__(256) void k_thalf2(const float* __restrict__ W1,
                                                _Float16* __restrict__ T1,
                                                const float* __restrict__ W2,
                                                _Float16* __restrict__ T2,
                                                int R1, int C1, int R2, int C2) {
    const float* src; _Float16* dh; int R, C;
    if (blockIdx.z == 0) { src = W1; dh = T1; R = R1; C = C1; }
    else                 { src = W2; dh = T2; R = R2; C = C2; }
    if ((int)blockIdx.x * 64 >= C || (int)blockIdx.y * 64 >= R) return;
    __shared__ float tile[64][65];
    int r0 = blockIdx.y * 64, c0 = blockIdx.x * 64;
    for (int i = threadIdx.x; i < 4096; i += 256) {
        int r = i >> 6, c = i & 63;
        tile[r][c] = src[(size_t)(r0 + r) * C + c0 + c];
    }
    __syncthreads();
    for (int i = threadIdx.x; i < 4096; i += 256) {
        int r = i >> 6, c = i & 63;
        dh[(size_t)(c0 + r) * R + r0 + c] = (_Float16)tile[c][r];
    }
}

// ---------------- gemm1: A = fp32 x cast in-kernel, B = fp16 plane -----------
// Epilogue: 64-wide slice-major C[(col>>6)*M + row][col&63].
__global__ __launch_bounds__(256) void k_gemm1(const float* __restrict__ X,
                                               const _Float16* __restrict__ B,
                                               const float* __restrict__ scale,
                                               _Float16* __restrict__ C,
                                               int M, int K, int Nc) {
    __shared__ __align__(16) _Float16 lds[2 * 128 * 64];  // Af | Bf
    _Float16* Afl = lds;
    _Float16* Bfl = lds + 8192;
    const int tid = threadIdx.x;
    const int m0 = blockIdx.x * 128, n0 = blockIdx.y * 128;
    const int w = tid >> 6, lane = tid & 63;
    const int wr = w >> 1, wc = w & 1;
    const int fr = lane & 15, kg = lane >> 4;

    const int arow = tid >> 1;            // staging row 0..127
    const int kf = (tid & 1) * 32;        // float offset within BK
    int rgA = m0 + arow; if (rgA >= M) rgA = M - 1;
    const float* ap0 = X + (size_t)rgA * K + kf;

    f32x4 acc[4][4] = {};

    for (int k0 = 0; k0 < K; k0 += 64) {
#pragma unroll
        for (int c = 0; c < 4; ++c) {
            const int r = c * 4 + w;              // 0..15, wave-uniform
            const int wch = r * 64 + lane;        // 0..1023
            const int row = wch >> 3, slot = wch & 7;
            const _Float16* gp = B + (size_t)(n0 + row) * K + k0 + ((slot ^ (row & 7)) << 3);
            __builtin_amdgcn_global_load_lds((const AS1 void*)gp,
                                             (AS3 void*)(Bfl + (size_t)r * 512), 16, 0, 0);
        }
        {
            const float* ap = ap0 + k0;
#pragma unroll
            for (int c2 = 0; c2 < 4; ++c2) {
                float4 q0 = *(const float4*)(ap + c2 * 8);
                float4 q1 = *(const float4*)(ap + c2 * 8 + 4);
                f16x8 hv;
                hv[0] = (_Float16)q0.x; hv[1] = (_Float16)q0.y;
                hv[2] = (_Float16)q0.z; hv[3] = (_Float16)q0.w;
                hv[4] = (_Float16)q1.x; hv[5] = (_Float16)q1.y;
                hv[6] = (_Float16)q1.z; hv[7] = (_Float16)q1.w;
                const int s = (tid & 1) * 4 + c2;
                *(f16x8*)&Afl[arow * 64 + ((s ^ (arow & 7)) << 3)] = hv;
            }
        }
        __syncthreads();
#pragma unroll
        for (int kc = 0; kc < 2; ++kc) {
            f16x8 a_f[4], b_f[4];
#pragma unroll
            for (int i = 0; i < 4; ++i) {
                const int ar = wr * 64 + i * 16 + fr;
                a_f[i] = *(const f16x8*)&Afl[ar * 64 + (((kc * 4 + kg) ^ (ar & 7)) << 3)];
                const int br = wc * 64 + i * 16 + fr;
                b_f[i] = *(const f16x8*)&Bfl[br * 64 + (((kc * 4 + kg) ^ (br & 7)) << 3)];
            }
#pragma unroll
            for (int i = 0; i < 4; ++i)
#pragma unroll
                for (int j = 0; j < 4; ++j)
                    acc[i][j] = __builtin_amdgcn_mfma_f32_16x16x32_f16(a_f[i], b_f[j], acc[i][j], 0, 0, 0);
        }
        __syncthreads();
    }
    // C/D layout: col=lane&15, row=(lane>>4)*4+reg (m89/m91); 64-slice store.
#pragma unroll
    for (int i = 0; i < 4; ++i) {
        const int rbase = m0 + wr * 64 + i * 16 + (lane >> 4) * 4;
#pragma unroll
        for (int r = 0; r < 4; ++r) {
            const int row = rbase + r;
            if (row < M) {
                const float s = scale[row];
#pragma unroll
                for (int j = 0; j < 4; ++j) {
                    const int col = n0 + wc * 64 + j * 16 + fr;
                    const size_t o = ((size_t)(col >> 6) * M + row) * 64 + (col & 63);
                    C[o] = (_Float16)(acc[i][j][r] * s);
                }
            }
        }
    }
}

// ---------------- gemm2: A,B fp16 planes via global_load_lds ----------------
__global__ __launch_bounds__(256) void k_gemm2(const _Float16* __restrict__ Ap,
                                               const _Float16* __restrict__ Bp,
                                               const float* __restrict__ scale,
                                               _Float16* __restrict__ C,
                                               int M, int K, int Nc) {
    __shared__ __align__(16) _Float16 lds[2 * 128 * 64];  // Af | Bf
    const int tid = threadIdx.x;
    const int m0 = blockIdx.x * 128, n0 = blockIdx.y * 128;
    const int w = tid >> 6, lane = tid & 63;
    const int wr = w >> 1, wc = w & 1;
    const int fr = lane & 15, kg = lane >> 4;

    f32x4 acc[4][4] = {};

    for (int k0 = 0; k0 < K; k0 += 64) {
#pragma unroll
        for (int c = 0; c < 8; ++c) {
            const int r = c * 4 + w;              // 0..31, wave-uniform
            const int p = r >> 4;                 // plane, wave-uniform
            const int wch = (r & 15) * 64 + lane; // 0..1023
            const int row = wch >> 3, slot = wch & 7;
            const int swz = (slot ^ (row & 7)) << 3;
            const _Float16* gp;
            if (p == 0) {
                int rg = m0 + row; if (rg >= M) rg = M - 1;
                gp = Ap + (size_t)rg * K + k0 + swz;
            } else {
                gp = Bp + (size_t)(n0 + row) * K + k0 + swz;
            }
            __builtin_amdgcn_global_load_lds((const AS1 void*)gp,
                                             (AS3 void*)(lds + (size_t)r * 512), 16, 0, 0);
        }
        __syncthreads();
#pragma unroll
        for (int kc = 0; kc < 2; ++kc) {
            f16x8 a_f[4], b_f[4];
#pragma unroll
            for (int i = 0; i < 4; ++i) {
                const int ar = wr * 64 + i * 16 + fr;
                a_f[i] = *(const f16x8*)&lds[ar * 64 + (((kc * 4 + kg) ^ (ar & 7)) << 3)];
                const int br = wc * 64 + i * 16 + fr;
                b_f[i] = *(const f16x8*)&lds[8192 + br * 64 + (((kc * 4 + kg) ^ (br & 7)) << 3)];
            }
#pragma unroll
            for (int i = 0; i < 4; ++i)
#pragma unroll
                for (int j = 0; j < 4; ++j)
                    acc[i][j] = __builtin_amdgcn_mfma_f32_16x16x32_f16(a_f[i], b_f[j], acc[i][j], 0, 0, 0);
        }
        __syncthreads();
    }
#pragma unroll
    for (int i = 0; i < 4; ++i) {
        const int rbase = m0 + wr * 64 + i * 16 + (lane >> 4) * 4;
#pragma unroll
        for (int r = 0; r < 4; ++r) {
            const int row = rbase + r;
            if (row < M) {
                const float s = scale[row];
#pragma unroll
                for (int j = 0; j < 4; ++j) {
                    const int col = n0 + wc * 64 + j * 16 + fr;
                    const size_t o = ((size_t)(col >> 6) * M + row) * 64 + (col & 63);
                    C[o] = (_Float16)(acc[i][j][r] * s);
                }
            }
        }
    }
}

// ---------------- aggregation: 128B granules, 4-deep (R12-proven) -----------
// Table slice-major [NSLICE][n][64] fp16 (pre-scaled by dinv[src]).
// One 8-LANE subgroup per (node,slice): lane li owns 8 feats (16B).
template <int NSLICE, bool OUTF16>
__global__ __launch_bounds__(256) void k_agg_gr(const _Float16* __restrict__ tbl0,
                                                const int* __restrict__ rowptr,
                                                const int* __restrict__ colv,
                                                const float* __restrict__ dinv,
                                                const float* __restrict__ bias,
                                                float* __restrict__ outf,
                                                _Float16* __restrict__ outh, int n) {
    constexpr int F = NSLICE * 64;
    const int slice = blockIdx.x;
    const int g = threadIdx.x >> 3;      // subgroup 0..31 = node within block
    const int li = threadIdx.x & 7;
    const int fb = li * 8;               // feature offset within slice
    const int wid = blockIdx.y * 32 + g;
    if (wid >= n) return;
    const _Float16* tbl = tbl0 + (size_t)slice * n * 64 + fb;

    float acc[8];
    {   // self row (pre-scaled by dinv[wid] in GEMM epilogue)
        f16x8 v = *(const f16x8*)(tbl + (size_t)wid * 64);
#pragma unroll
        for (int j = 0; j < 8; ++j) acc[j] = (float)v[j];
    }
    const int p0 = rowptr[wid], p1 = rowptr[wid + 1];
    int p = p0;
    for (; p + 4 <= p1; p += 4) {
        int s0 = colv[p], s1 = colv[p + 1], s2 = colv[p + 2], s3 = colv[p + 3];
        f16x8 v0 = *(const f16x8*)(tbl + (size_t)s0 * 64);
        f16x8 v1 = *(const f16x8*)(tbl + (size_t)s1 * 64);
        f16x8 v2 = *(const f16x8*)(tbl + (size_t)s2 * 64);
        f16x8 v3 = *(const f16x8*)(tbl + (size_t)s3 * 64);
#pragma unroll
        for (int j = 0; j < 8; ++j)
            acc[j] += ((float)v0[j] + (float)v1[j]) + ((float)v2[j] + (float)v3[j]);
    }
    for (; p < p1; ++p) {
        f16x8 v = *(const f16x8*)(tbl + (size_t)colv[p] * 64);
#pragma unroll
        for (int j = 0; j < 8; ++j) acc[j] += (float)v[j];
    }
    const float di = dinv[wid];
    float r[8];
#pragma unroll
    for (int j = 0; j < 8; ++j) {
        float t = di * acc[j] + bias[slice * 64 + fb + j];
        r[j] = t > 0.f ? t : 0.f;
    }
    const size_t o = (size_t)wid * F + slice * 64 + fb;
    if constexpr (OUTF16) {
        f16x8 hv;
#pragma unroll
        for (int j = 0; j < 8; ++j) hv[j] = (_Float16)r[j];
        *(f16x8*)(outh + o) = hv;
    } else {
        float* op = outf + o;
        *(float4*)(op)     = make_float4(r[0], r[1], r[2], r[3]);
        *(float4*)(op + 4) = make_float4(r[4], r[5], r[6], r[7]);
    }
}

extern "C" void kernel_launch(void* const* d_in, const int* in_sizes, int n_in,
                              void* d_out, int out_size, void* d_ws, size_t ws_size,
                              hipStream_t stream) {
    const float* x  = (const float*)d_in[0];
    const int*   ei = (const int*)d_in[1];
    const float* W1 = (const float*)d_in[2];
    const float* b1 = (const float*)d_in[3];
    const float* W2 = (const float*)d_in[4];
    const float* b2 = (const float*)d_in[5];

    const int HID = in_sizes[3];            // 256
    const int IN  = in_sizes[2] / HID;      // 256
    const int OUT = in_sizes[5];            // 128
    const int N   = in_sizes[0] / IN;       // 50000
    const int E   = in_sizes[1] / 2;        // 800000

    const int* src = ei;
    const int* dst = ei + E;

    char* wsb = (char*)d_ws;
    size_t off = 0;
    auto carve = [&](size_t bytes) -> char* {
        char* p = wsb + off;
        off += (bytes + 255) & ~(size_t)255;
        return p;
    };
    _Float16* h1  = (_Float16*)carve((size_t)N * HID * 2);  // row-major fp16
    _Float16* hsb = (_Float16*)carve((size_t)N * HID * 2);  // slice-major [4][N][64]
    _Float16* gsb = (_Float16*)carve((size_t)N * OUT * 2);  // slice-major [2][N][64]
    float* dinv   = (float*)carve((size_t)N * 4);
    int*   rowptr = (int*)carve((size_t)(N + 1) * 4);
    int*   colv   = (int*)carve((size_t)E * 4);
    long long* ebuf = (long long*)carve((size_t)256 * BCAP * 8);
    int*   cursor = (int*)carve(1024);
    _Float16* W1Th = (_Float16*)carve((size_t)IN * HID * 2);
    _Float16* W2Th = (_Float16*)carve((size_t)HID * OUT * 2);
    (void)ws_size; (void)n_in; (void)out_size;

    const int nbkt = (N + 255) >> 8;   // 196 buckets
    const int ybN = (N + 31) / 32;     // one 8-lane subgroup per node

    // CSR via bucket sort (no per-edge global atomics)
    hipMemsetAsync(cursor, 0, 1024, stream);
    k_scatter<<<256, 256, 0, stream>>>(src, dst, cursor, ebuf, E);
    k_bktsort<<<nbkt, 256, 0, stream>>>(ebuf, cursor, rowptr, colv, dinv, N, E);

    // merged weight transposes (fp16 planes)
    k_thalf2<<<dim3(4, 4, 2), 256, 0, stream>>>(W1, W1Th, W2, W2Th, IN, HID, HID, OUT);

    // layer 1 (x fp16-cast fused into gemm1)
    k_gemm1<<<dim3((N + 127) / 128, HID / 128), 256, 0, stream>>>(
        x, W1Th, dinv, hsb, N, IN, HID);
    k_agg_gr<4, true><<<dim3(4, ybN), 256, 0, stream>>>(
        hsb, rowptr, colv, dinv, b1, nullptr, h1, N);
    // layer 2
    k_gemm2<<<dim3((N + 127) / 128, OUT / 128), 256, 0, stream>>>(
        h1, W2Th, dinv, gsb, N, HID, OUT);
    k_agg_gr<2, false><<<dim3(2, ybN), 256, 0, stream>>>(
        gsb, rowptr, colv, dinv, b2, (float*)d_out, nullptr, N);
}